// Round 3
// baseline (13337.741 us; speedup 1.0000x reference)
//
#include <hip/hip_runtime.h>
#include <math.h>

// Problem constants (fixed by setup_inputs)
#define Bz 64
#define Tz 1024
#define Dz 512
#define Hz 256
#define Gz 1024   // 4*H
#define Kz 20

// ws layout (dwords):
//  [0..7]     gcnt[8]   per-(dir, steppair%4) completed-tile counters (monotone)
//  [8..39]    prog[32]  per-(dir,bs) rec progress (monotone)
//  [40..255]  pad
//  [256 ..)   xbuf: u64[786432] (6 MB)  rec partial exchange, stamped
//  then       Gring: f32[8][2][1024][64] (4 MB) gate ring, 8 steps deep
#define CTRL_DW  256
#define XBUF_U64 786432
#define ZERO_DW  (CTRL_DW + XBUF_U64 * 2)
#define RING_DW  (8 * 2 * 1024 * 64)

__device__ __forceinline__ float sigf(float x) { return 1.0f / (1.0f + __expf(-x)); }

__device__ __forceinline__ unsigned long long packsv(float v, unsigned st) {
    return ((unsigned long long)st << 32) | (unsigned long long)__float_as_uint(v);
}
__device__ __forceinline__ unsigned long long pack2(float a, float b) {
    return ((unsigned long long)__float_as_uint(b) << 32) |
           (unsigned long long)__float_as_uint(a);
}

// ---------------------------------------------------------------------------
__global__ __launch_bounds__(256) void init_ws(int* p) {
    int i = blockIdx.x * 256 + threadIdx.x;
    if (i < ZERO_DW) p[i] = 0;
}

// ---------------------------------------------------------------------------
// Fused persistent kernel: 256 blocks x 512 threads, exactly 1 block/CU.
//
// Blocks 0..127  : REC  (dir 2 x kq 4 x bs 16). Block owns batches 4bs..4bs+3,
//   h-range = k-range [64kq,64kq+64). W_hh rows x its 64 k in REGISTERS
//   (thread: 2 rows x 64 k = 128 regs). Per step: k-loop -> ship stamped
//   partial gate sums to 3 peers via xbuf u64{f32,stamp} (parity ring, agent
//   scope, proven v5 protocol) -> gather -> activations -> h_l in LDS.
//   Gates' x-contribution read from Gring (gated by gcnt). Publishes prog.
// Blocks 128..255: GEMM (dir 2 x rowtile 16 x phase 4). W_ih 64x512 tile in
//   LDS (loaded once). Iterates steppairs sp = phase, phase+4, ...: stages x
//   (2 steps x 64 batches), FMA 64x128x512, writes Gring slot as u64 agent
//   stores, vmcnt(0), then atomicAdd gcnt. Ring overwrite gated on rec prog
//   (min over 16 groups >= 2sp-6), which by the stamp induction implies all
//   G reads of the evicted steps completed.
// ---------------------------------------------------------------------------
__global__ __launch_bounds__(512, 1) void fused_lstm(
    const float* __restrict__ x,
    const float* __restrict__ Wif, const float* __restrict__ Whf,
    const float* __restrict__ bf,
    const float* __restrict__ Wib, const float* __restrict__ Whb,
    const float* __restrict__ bb,
    float* __restrict__ out1, int* __restrict__ ctrl)
{
    __shared__ __align__(16) float smem[34880];   // 139,520 B
    int* gcnt = ctrl;          // 8
    int* prog = ctrl + 8;      // 32
    unsigned long long* xbuf = (unsigned long long*)(ctrl + CTRL_DW);
    float* Gring = (float*)(ctrl + CTRL_DW + XBUF_U64 * 2);

    const int tid = threadIdx.x;
    const int blk = blockIdx.x;

    if (blk < 128) {
        // ================= REC =================
        const int dir = blk >> 6;
        const int kq  = (blk >> 4) & 3;
        const int bs  = blk & 15;
        const float* __restrict__ Whh = dir ? Whb : Whf;

        float* h_l   = smem;          // [64][4]
        float* selfP = smem + 256;    // [256][4]
        float* gl    = smem + 1280;   // [256][4]

        // register-resident W: rows r0, r0+1, k in [64kq, 64kq+64)
        const int r0 = tid * 2;
        float w0[64], w1[64];
        {
            const float* p0 = Whh + (size_t)r0 * Hz + kq * 64;
            const float* p1 = p0 + Hz;
#pragma unroll
            for (int i = 0; i < 16; ++i) {
                float4 a = *(const float4*)(p0 + 4 * i);
                float4 c = *(const float4*)(p1 + 4 * i);
                w0[4*i+0]=a.x; w0[4*i+1]=a.y; w0[4*i+2]=a.z; w0[4*i+3]=a.w;
                w1[4*i+0]=c.x; w1[4*i+1]=c.y; w1[4*i+2]=c.z; w1[4*i+3]=c.w;
            }
        }
        const int dst  = (r0 >> 6) & 3;
        const int rowp = (r0 >> 8) * 64 + (r0 & 63);
        const int srci = kq - (kq > dst ? 1 : 0);

        const int arow  = tid >> 1;                    // phase-A row' 0..255
        const int bp    = tid & 1;                     // batch pair
        const int growA = (arow >> 6) * 256 + kq * 64 + (arow & 63);
        const int bglo  = bs * 4;

        size_t ob[2], ib[2];
#pragma unroll
        for (int p = 0; p < 2; ++p) {
            size_t o = ((((size_t)p * 2 + dir) * 16 + bs) * 4 + dst) * 3 + srci;
            ob[p] = o * 1024 + (size_t)rowp * 4;
            size_t q = ((((size_t)p * 2 + dir) * 16 + bs) * 4 + kq) * 3;
            ib[p] = q * 1024 + (size_t)arow * 4 + 2 * bp;
        }

        for (int i = tid; i < 256; i += 512) h_l[i] = 0.0f;
        float c_reg = 0.0f;
        const int rr = tid >> 2, bb2 = tid & 3;        // phase-B ids (tid<256)
        __syncthreads();

        for (int s = 0; s < Tz; ++s) {
            const unsigned stamp = (unsigned)(s + 1);
            const int par = s & 1;

            if ((s & 1) == 0) {   // wait for gate tile pair
                const int sp = s >> 1;
                const int tgt = ((sp >> 2) + 1) * 16;
                if (tid < 64) {
                    const int* gp = gcnt + dir * 4 + (sp & 3);
                    while (__hip_atomic_load(gp, __ATOMIC_RELAXED,
                                             __HIP_MEMORY_SCOPE_AGENT) < tgt)
                        __builtin_amdgcn_s_sleep(2);
                }
                __syncthreads();
            }

            // G prefetch (2 batches packed in one u64)
            const unsigned long long* Gp = (const unsigned long long*)
                (Gring + ((size_t)((s & 7) * 2 + dir) * 1024 + growA) * 64
                       + bglo + 2 * bp);
            unsigned long long gv = __hip_atomic_load(Gp, __ATOMIC_RELAXED,
                                                      __HIP_MEMORY_SCOPE_AGENT);

            // k-loop: 2 rows x 4 batches, W in regs, h broadcast from LDS
            float a0[4] = {}, a1[4] = {};
#pragma unroll
            for (int k = 0; k < 64; ++k) {
                const float4 hv = *(const float4*)(h_l + k * 4);
                const float wa = w0[k], wc = w1[k];
                a0[0] = fmaf(wa, hv.x, a0[0]); a0[1] = fmaf(wa, hv.y, a0[1]);
                a0[2] = fmaf(wa, hv.z, a0[2]); a0[3] = fmaf(wa, hv.w, a0[3]);
                a1[0] = fmaf(wc, hv.x, a1[0]); a1[1] = fmaf(wc, hv.y, a1[1]);
                a1[2] = fmaf(wc, hv.z, a1[2]); a1[3] = fmaf(wc, hv.w, a1[3]);
            }

            // ship partials
            if (dst == kq) {
                *(float4*)(selfP + rowp * 4)     = make_float4(a0[0],a0[1],a0[2],a0[3]);
                *(float4*)(selfP + rowp * 4 + 4) = make_float4(a1[0],a1[1],a1[2],a1[3]);
            } else {
                unsigned long long* op = xbuf + ob[par];
#pragma unroll
                for (int j = 0; j < 4; ++j)
                    __hip_atomic_store(op + j, packsv(a0[j], stamp),
                                       __ATOMIC_RELAXED, __HIP_MEMORY_SCOPE_AGENT);
#pragma unroll
                for (int j = 0; j < 4; ++j)
                    __hip_atomic_store(op + 4 + j, packsv(a1[j], stamp),
                                       __ATOMIC_RELAXED, __HIP_MEMORY_SCOPE_AGENT);
            }
            __syncthreads();

            // phase A: gather 3 peers x 2 u64, stamp-spin
            {
                const unsigned long long* i0 = xbuf + ib[par];
                const unsigned long long* ps[6] =
                    { i0, i0 + 1, i0 + 1024, i0 + 1025, i0 + 2048, i0 + 2049 };
                unsigned long long v[6];
#pragma unroll
                for (int j = 0; j < 6; ++j)
                    v[j] = __hip_atomic_load(ps[j], __ATOMIC_RELAXED,
                                             __HIP_MEMORY_SCOPE_AGENT);
                for (;;) {
                    bool ok = true;
#pragma unroll
                    for (int j = 0; j < 6; ++j)
                        ok &= ((unsigned)(v[j] >> 32) == stamp);
                    if (ok) break;
                    __builtin_amdgcn_s_sleep(1);
#pragma unroll
                    for (int j = 0; j < 6; ++j)
                        if ((unsigned)(v[j] >> 32) != stamp)
                            v[j] = __hip_atomic_load(ps[j], __ATOMIC_RELAXED,
                                                     __HIP_MEMORY_SCOPE_AGENT);
                }
                gl[arow * 4 + 2 * bp] =
                    __uint_as_float((unsigned)gv) + selfP[arow * 4 + 2 * bp]
                    + __uint_as_float((unsigned)v[0])
                    + __uint_as_float((unsigned)v[2])
                    + __uint_as_float((unsigned)v[4]);
                gl[arow * 4 + 2 * bp + 1] =
                    __uint_as_float((unsigned)(gv >> 32)) + selfP[arow * 4 + 2 * bp + 1]
                    + __uint_as_float((unsigned)v[1])
                    + __uint_as_float((unsigned)v[3])
                    + __uint_as_float((unsigned)v[5]);
            }
            __syncthreads();

            // phase B: activations (256 threads own 64 h x 4 b)
            float hv_s = 0.0f;
            if (tid < 256) {
                const float gi = sigf(gl[rr * 4 + bb2]);
                const float gf = sigf(gl[(64 + rr) * 4 + bb2]);
                const float gg = tanhf(gl[(128 + rr) * 4 + bb2]);
                const float go = sigf(gl[(192 + rr) * 4 + bb2]);
                c_reg = gf * c_reg + gi * gg;
                hv_s = go * tanhf(c_reg);
                h_l[rr * 4 + bb2] = hv_s;
            }
            __syncthreads();
            if (kq == 0 && tid == 0)
                __hip_atomic_store(prog + dir * 16 + bs, s,
                                   __ATOMIC_RELAXED, __HIP_MEMORY_SCOPE_AGENT);
            if (tid < 256) {
                const int tt = dir ? (Tz - 1 - s) : s;
                out1[((size_t)(bglo + bb2) * Tz + tt) * Dz + dir * Hz + kq * 64 + rr] = hv_s;
            }
        }
    } else {
        // ================= GEMM =================
        const int g2      = blk - 128;
        const int rowtile = g2 & 15;
        const int dir     = (g2 >> 4) & 1;
        const int phase   = (g2 >> 5) & 3;
        const float* __restrict__ Wih  = dir ? Wib : Wif;
        const float* __restrict__ bias = dir ? bb : bf;

        float* Bs  = smem;            // [16][132]
        float* A_l = smem + 2112;     // [512][64]  W_ih^T tile

        const int mg = tid >> 5;      // 0..15 row-group
        const int ng = tid & 31;      // 0..31 col-group
        const float4 bias4 = *(const float4*)(bias + rowtile * 64 + mg * 4);

        // load A tile once: A_l[k][r] = Wih[rowtile*64+r][k]
        for (int idx = tid * 4; idx < 64 * 512; idx += 2048) {
            const int r = idx >> 9, k = idx & 511;
            const float4 a = *(const float4*)(Wih + (size_t)(rowtile * 64 + r) * Dz + k);
            A_l[(k + 0) * 64 + r] = a.x; A_l[(k + 1) * 64 + r] = a.y;
            A_l[(k + 2) * 64 + r] = a.z; A_l[(k + 3) * 64 + r] = a.w;
        }
        __syncthreads();

        const int nn   = tid & 127;        // staging column 0..127
        const int ko   = (tid >> 7) * 4;   // staging k-offset
        const int bcol = nn & 63;
        const int slx  = nn >> 6;
        const int ssl  = ng >> 4;          // store sl
        const int bc0  = (ng & 15) * 4;    // store batch base

        for (int sp = phase; sp < 512; sp += 4) {
            const int s0 = 2 * sp;
            const int ttx = dir ? (Tz - 1 - (s0 + slx)) : (s0 + slx);
            const float* xp = x + ((size_t)bcol * Tz + ttx) * Dz;

            float4 bq = *(const float4*)(xp + ko);
            float acc[4][4] = {};
            for (int kt = 0; kt < 512; kt += 16) {
                __syncthreads();
                Bs[(ko + 0) * 132 + nn] = bq.x;
                Bs[(ko + 1) * 132 + nn] = bq.y;
                Bs[(ko + 2) * 132 + nn] = bq.z;
                Bs[(ko + 3) * 132 + nn] = bq.w;
                __syncthreads();
                if (kt + 16 < 512) bq = *(const float4*)(xp + kt + 16 + ko);
#pragma unroll
                for (int kk = 0; kk < 16; ++kk) {
                    const float4 av = *(const float4*)(A_l + (kt + kk) * 64 + mg * 4);
                    const float4 bv = *(const float4*)(Bs + kk * 132 + ng * 4);
                    acc[0][0]=fmaf(av.x,bv.x,acc[0][0]); acc[0][1]=fmaf(av.x,bv.y,acc[0][1]);
                    acc[0][2]=fmaf(av.x,bv.z,acc[0][2]); acc[0][3]=fmaf(av.x,bv.w,acc[0][3]);
                    acc[1][0]=fmaf(av.y,bv.x,acc[1][0]); acc[1][1]=fmaf(av.y,bv.y,acc[1][1]);
                    acc[1][2]=fmaf(av.y,bv.z,acc[1][2]); acc[1][3]=fmaf(av.y,bv.w,acc[1][3]);
                    acc[2][0]=fmaf(av.z,bv.x,acc[2][0]); acc[2][1]=fmaf(av.z,bv.y,acc[2][1]);
                    acc[2][2]=fmaf(av.z,bv.z,acc[2][2]); acc[2][3]=fmaf(av.z,bv.w,acc[2][3]);
                    acc[3][0]=fmaf(av.w,bv.x,acc[3][0]); acc[3][1]=fmaf(av.w,bv.y,acc[3][1]);
                    acc[3][2]=fmaf(av.w,bv.z,acc[3][2]); acc[3][3]=fmaf(av.w,bv.w,acc[3][3]);
                }
            }

            // gate ring-slot overwrite on rec progress (skip first 4 pairs)
            if (sp >= 4) {
                const int tgt = 2 * sp - 6;
                if (tid < 64) {
                    for (;;) {
                        int pv = (tid < 16)
                            ? __hip_atomic_load(prog + dir * 16 + tid,
                                                __ATOMIC_RELAXED, __HIP_MEMORY_SCOPE_AGENT)
                            : 0x7fffffff;
                        if (__all(pv >= tgt)) break;
                        __builtin_amdgcn_s_sleep(2);
                    }
                }
            }
            __syncthreads();

            // store tile (u64 agent stores), drain, signal
            const int slot = (s0 + ssl) & 7;
            float* gbase = Gring + ((size_t)(slot * 2 + dir) * 1024
                                    + rowtile * 64 + mg * 4) * 64 + bc0;
#pragma unroll
            for (int i = 0; i < 4; ++i) {
                const float bv4 = (i == 0) ? bias4.x : (i == 1) ? bias4.y
                                 : (i == 2) ? bias4.z : bias4.w;
                unsigned long long* gp = (unsigned long long*)(gbase + (size_t)i * 64);
                __hip_atomic_store(gp,     pack2(acc[i][0] + bv4, acc[i][1] + bv4),
                                   __ATOMIC_RELAXED, __HIP_MEMORY_SCOPE_AGENT);
                __hip_atomic_store(gp + 1, pack2(acc[i][2] + bv4, acc[i][3] + bv4),
                                   __ATOMIC_RELAXED, __HIP_MEMORY_SCOPE_AGENT);
            }
            asm volatile("s_waitcnt vmcnt(0)" ::: "memory");
            __syncthreads();
            if (tid == 0)
                __hip_atomic_fetch_add(gcnt + dir * 4 + (sp & 3), 1,
                                       __ATOMIC_RELAXED, __HIP_MEMORY_SCOPE_AGENT);
        }
    }
}

// ---------------------------------------------------------------------------
// Head: logits -> 20 smallest (softmax is monotone) -> indices + sgn_mask.
// ---------------------------------------------------------------------------
__global__ __launch_bounds__(256) void head_kernel(
    const float* __restrict__ out1, const float* __restrict__ lin_w,
    const float* __restrict__ lin_b, const unsigned char* __restrict__ mask8,
    float* __restrict__ out0, float* __restrict__ out2)
{
    __shared__ __align__(16) float lw[Dz];
    __shared__ float llog[Tz];
    __shared__ unsigned char hit[Tz];
    __shared__ float redv[4];
    __shared__ int   redi[4];

    const int tid = threadIdx.x;
    const int bb  = blockIdx.x;
    for (int i = tid; i < Dz; i += 256) lw[i] = lin_w[i];
    for (int i = tid; i < Tz; i += 256) hit[i] = 0;
    __syncthreads();

    const int w = tid >> 6, lane = tid & 63;
    const float lbv = lin_b[0];
    for (int t = w; t < Tz; t += 4) {
        const float* rp = out1 + ((size_t)bb * Tz + t) * Dz + lane * 8;
        float4 a0 = *(const float4*)rp;
        float4 a1 = *(const float4*)(rp + 4);
        const float* wp = lw + lane * 8;
        float ps = a0.x * wp[0] + a0.y * wp[1] + a0.z * wp[2] + a0.w * wp[3]
                 + a1.x * wp[4] + a1.y * wp[5] + a1.z * wp[6] + a1.w * wp[7];
        for (int o = 32; o; o >>= 1) ps += __shfl_down(ps, o);
        if (lane == 0) llog[t] = ps + lbv;
    }
    __syncthreads();

    for (int it = 0; it < Kz; ++it) {
        float bv = 3.4e38f; int bi = Tz - 1;
        for (int t = tid; t < Tz; t += 256) {
            float v = llog[t];
            if (v < bv) { bv = v; bi = t; }
        }
        for (int o = 32; o; o >>= 1) {
            float ov = __shfl_down(bv, o);
            int   oi = __shfl_down(bi, o);
            if (ov < bv || (ov == bv && oi < bi)) { bv = ov; bi = oi; }
        }
        if (lane == 0) { redv[w] = bv; redi[w] = bi; }
        __syncthreads();
        if (tid == 0) {
            for (int qq = 1; qq < 4; ++qq)
                if (redv[qq] < bv || (redv[qq] == bv && redi[qq] < bi)) { bv = redv[qq]; bi = redi[qq]; }
            out0[bb * Kz + it] = (float)bi;
            llog[bi] = 3.4e38f;
            hit[bi] = 1;
        }
        __syncthreads();
    }
    for (int t = tid; t < Tz; t += 256) {
        bool mv = mask8[(size_t)bb * Tz + t] != 0;
        out2[(size_t)bb * Tz + t] = (mv && !hit[t]) ? 1.0f : 0.0f;
    }
}

// ---------------------------------------------------------------------------
// In-place LayerNorm over last dim (512), eps=1e-5. One wave per row.
// ---------------------------------------------------------------------------
__global__ __launch_bounds__(256) void ln_kernel(
    float* __restrict__ out1, const float* __restrict__ ln_g,
    const float* __restrict__ ln_b)
{
    const int tid = threadIdx.x;
    const int w = tid >> 6, lane = tid & 63;
    const size_t row = (size_t)blockIdx.x * 4 + w;
    float* rp = out1 + row * Dz + lane * 8;
    float4 a0 = *(float4*)rp;
    float4 a1 = *(float4*)(rp + 4);
    float s  = a0.x + a0.y + a0.z + a0.w + a1.x + a1.y + a1.z + a1.w;
    float sq = a0.x*a0.x + a0.y*a0.y + a0.z*a0.z + a0.w*a0.w
             + a1.x*a1.x + a1.y*a1.y + a1.z*a1.z + a1.w*a1.w;
    for (int o = 32; o; o >>= 1) { s += __shfl_down(s, o); sq += __shfl_down(sq, o); }
    s  = __shfl(s, 0);
    sq = __shfl(sq, 0);
    const float mu  = s * (1.0f / Dz);
    const float var = sq * (1.0f / Dz) - mu * mu;
    const float rs  = rsqrtf(var + 1e-5f);
    const float* gp = ln_g + lane * 8;
    const float* bp = ln_b + lane * 8;
    a0.x = (a0.x - mu) * rs * gp[0] + bp[0];
    a0.y = (a0.y - mu) * rs * gp[1] + bp[1];
    a0.z = (a0.z - mu) * rs * gp[2] + bp[2];
    a0.w = (a0.w - mu) * rs * gp[3] + bp[3];
    a1.x = (a1.x - mu) * rs * gp[4] + bp[4];
    a1.y = (a1.y - mu) * rs * gp[5] + bp[5];
    a1.z = (a1.z - mu) * rs * gp[6] + bp[6];
    a1.w = (a1.w - mu) * rs * gp[7] + bp[7];
    *(float4*)rp = a0;
    *(float4*)(rp + 4) = a1;
}

// ---------------------------------------------------------------------------
extern "C" void kernel_launch(void* const* d_in, const int* in_sizes, int n_in,
                              void* d_out, int out_size, void* d_ws, size_t ws_size,
                              hipStream_t stream)
{
    (void)in_sizes; (void)n_in; (void)out_size; (void)ws_size;
    const float* x     = (const float*)d_in[0];
    const float* Wif   = (const float*)d_in[1];
    const float* Whf   = (const float*)d_in[2];
    const float* bf    = (const float*)d_in[3];
    const float* Wib   = (const float*)d_in[4];
    const float* Whb   = (const float*)d_in[5];
    const float* bb    = (const float*)d_in[6];
    const float* lin_w = (const float*)d_in[7];
    const float* lin_b = (const float*)d_in[8];
    const float* ln_g  = (const float*)d_in[9];
    const float* ln_b  = (const float*)d_in[10];
    const unsigned char* mask8 = (const unsigned char*)d_in[11];

    int* ctrl = (int*)d_ws;   // total ws use: (256 + 1572864 + 1048576)*4 ≈ 10.0 MB

    float* out0 = (float*)d_out;
    float* out1 = out0 + (size_t)Bz * Kz;
    float* out2 = out1 + (size_t)Bz * Tz * Dz;

    init_ws<<<dim3((ZERO_DW + 255) / 256), 256, 0, stream>>>(ctrl);
    fused_lstm<<<dim3(256), 512, 0, stream>>>(x, Wif, Whf, bf, Wib, Whb, bb,
                                              out1, ctrl);
    head_kernel<<<dim3(Bz), 256, 0, stream>>>(out1, lin_w, lin_b, mask8, out0, out2);
    ln_kernel<<<dim3((Bz * Tz) / 4), 256, 0, stream>>>(out1, ln_g, ln_b);
}